// Round 2
// baseline (339.480 us; speedup 1.0000x reference)
//
#include <hip/hip_runtime.h>

// RelativeGridAttention: (B,H,Q,D)=(2,8,4096,32), grid 32x32 -> 1024 positions.
// v2 (resubmit after infra failure): operand-swapped MFMA so each lane owns 4
// CONSECUTIVE output columns of one query row -> float4 stores, float4 bias
// loads, 2-shuffle softmax reduction. Softmax denominator via pass-1 sum,
// pass-2 RECOMPUTES scores (no 128-reg E cache) -> VGPR < 128, 512-thread
// blocks, 4 waves/SIMD (2x occupancy vs v1).
namespace {
constexpr int B_ = 2, H_ = 8, Q_ = 4096, D_ = 32;
constexpr int NPOS = 1024;            // 32*32 key positions
constexpr int NB = 63;                // 2*32-1 rel_bias side
constexpr int NT = 512;               // 8 waves per block
constexpr int QCHUNK = 128;           // 8 waves * 16 query rows
constexpr float SCALE = 0.17677669529663687f;     // 1/sqrt(32)
constexpr float LOG2E = 1.4426950408889634f;
constexpr float C1 = SCALE * LOG2E;
}

typedef __attribute__((ext_vector_type(8))) short short8;   // 8 bf16, 4 VGPRs
typedef __attribute__((ext_vector_type(4))) float float4v;  // MFMA C/D

__device__ __forceinline__ unsigned short f2bf(float f) {   // fp32 -> bf16 RNE
  unsigned u = __float_as_uint(f);
  u += 0x7fffu + ((u >> 16) & 1u);
  return (unsigned short)(u >> 16);
}

__device__ __forceinline__ float fexp2(float x) {
#if defined(__has_builtin)
#if __has_builtin(__builtin_amdgcn_exp2f)
  return __builtin_amdgcn_exp2f(x);
#else
  return exp2f(x);
#endif
#else
  return exp2f(x);
#endif
}

__device__ __forceinline__ float frcp(float x) {
#if defined(__has_builtin)
#if __has_builtin(__builtin_amdgcn_rcpf)
  return __builtin_amdgcn_rcpf(x);
#else
  return 1.0f / x;
#endif
#else
  return 1.0f / x;
#endif
}

__global__ __launch_bounds__(NT, 4)
void rga_kernel(const float* __restrict__ queries,
                const float* __restrict__ keys,
                const int*   __restrict__ pos,
                const float* __restrict__ rel_bias,
                float* __restrict__ out) {
  __shared__ __align__(16) unsigned short klds[NPOS * D_];   // 64 KB bf16 keys

  const int t    = threadIdx.x;
  const int lane = t & 63;
  const int w    = t >> 6;          // wave id 0..7
  const int m    = lane & 15;       // query-row-within-tile AND D-col for frags
  const int quad = lane >> 4;       // 0..3
  const int h  = blockIdx.y;
  const int b  = blockIdx.z;
  const int bh = b * H_ + h;
  const int q0 = blockIdx.x * QCHUNK;

  // ---- stage keys slice (b,h) as bf16 into LDS (coalesced, once) ----
  {
    const float4* src = (const float4*)(keys + (size_t)bh * (NPOS * D_));
    #pragma unroll
    for (int i = 0; i < (NPOS * D_ / 4) / NT; ++i) {          // 16 iters
      float4 v = src[i * NT + t];
      unsigned lo = (unsigned)f2bf(v.x) | ((unsigned)f2bf(v.y) << 16);
      unsigned hi = (unsigned)f2bf(v.z) | ((unsigned)f2bf(v.w) << 16);
      ((uint2*)klds)[i * NT + t] = make_uint2(lo, hi);
    }
  }
  __syncthreads();

  const int qrow = q0 + w * 16 + m;   // this lane's query row

  // A fragment (used as MFMA *src1*): query row qrow, k = quad*8 + j
  short8 afrag;
  {
    const float* qp = queries + ((size_t)(bh * Q_) + qrow) * D_ + quad * 8;
    float4 x = *(const float4*)(qp);
    float4 y = *(const float4*)(qp + 4);
    afrag[0] = (short)f2bf(x.x); afrag[1] = (short)f2bf(x.y);
    afrag[2] = (short)f2bf(x.z); afrag[3] = (short)f2bf(x.w);
    afrag[4] = (short)f2bf(y.x); afrag[5] = (short)f2bf(y.y);
    afrag[6] = (short)f2bf(y.z); afrag[7] = (short)f2bf(y.w);
  }

  // per-lane bias base: row q = qrow, output col p = n*16 + quad*4 + r
  // bias idx = (p>>5 - py + 31)*63 + ((p&31) - px + 31)
  //          = [ (31-py)*63 + (31-px) + quad*4 ] + (n>>1)*63 + ((n&1)<<4) + r
  const float* bbase;
  {
    int2 p = *(const int2*)(pos + ((size_t)b * Q_ + qrow) * 2);
    bbase = rel_bias + (size_t)h * (NB * NB)
          + (31 - p.x) * NB + (31 - p.y) + quad * 4;
  }

  const unsigned short* kbase = klds + m * D_ + quad * 8;

  // ---- pass 1: row sum of exp ----
  float sum = 0.f;
  #pragma unroll
  for (int n = 0; n < NPOS / 16; ++n) {
    const short8 kf = *(const short8*)(kbase + n * 512);
    // swapped operands: acc[r] = S[qrow][n*16 + quad*4 + r]
    float4v acc = __builtin_amdgcn_mfma_f32_16x16x32_bf16(
        kf, afrag, (float4v){0.f, 0.f, 0.f, 0.f}, 0, 0, 0);
    float4v bv;
    __builtin_memcpy(&bv, bbase + (n >> 1) * NB + ((n & 1) << 4), 16);
    float e0 = fexp2(acc[0] * C1 + bv[0] * LOG2E);
    float e1 = fexp2(acc[1] * C1 + bv[1] * LOG2E);
    float e2 = fexp2(acc[2] * C1 + bv[2] * LOG2E);
    float e3 = fexp2(acc[3] * C1 + bv[3] * LOG2E);
    sum += (e0 + e1) + (e2 + e3);
  }
  // full row sum: combine the 4 quads holding the same query row
  sum += __shfl_xor(sum, 16, 64);
  sum += __shfl_xor(sum, 32, 64);
  const float rinv = frcp(sum);

  // ---- pass 2: recompute and store normalized row (float4, nontemporal) ----
  float* orow = out + ((size_t)(bh * Q_) + qrow) * NPOS + quad * 4;
  #pragma unroll
  for (int n = 0; n < NPOS / 16; ++n) {
    const short8 kf = *(const short8*)(kbase + n * 512);
    float4v acc = __builtin_amdgcn_mfma_f32_16x16x32_bf16(
        kf, afrag, (float4v){0.f, 0.f, 0.f, 0.f}, 0, 0, 0);
    float4v bv;
    __builtin_memcpy(&bv, bbase + (n >> 1) * NB + ((n & 1) << 4), 16);
    float4v ev;
    ev[0] = fexp2(acc[0] * C1 + bv[0] * LOG2E) * rinv;
    ev[1] = fexp2(acc[1] * C1 + bv[1] * LOG2E) * rinv;
    ev[2] = fexp2(acc[2] * C1 + bv[2] * LOG2E) * rinv;
    ev[3] = fexp2(acc[3] * C1 + bv[3] * LOG2E) * rinv;
    __builtin_nontemporal_store(ev, (float4v*)(orow + n * 16));
  }
}

extern "C" void kernel_launch(void* const* d_in, const int* in_sizes, int n_in,
                              void* d_out, int out_size, void* d_ws, size_t ws_size,
                              hipStream_t stream) {
  const float* queries  = (const float*)d_in[0];
  const float* keys     = (const float*)d_in[1];
  const int*   pos      = (const int*)d_in[2];
  const float* rel_bias = (const float*)d_in[3];
  float* out = (float*)d_out;

  dim3 grid(Q_ / QCHUNK, H_, B_);   // 32 x 8 x 2 = 512 blocks = 2/CU exactly
  dim3 block(NT);
  hipLaunchKernelGGL(rga_kernel, grid, block, 0, stream,
                     queries, keys, pos, rel_bias, out);
}

// Round 3
// 331.096 us; speedup vs baseline: 1.0253x; 1.0253x over previous
//
#include <hip/hip_runtime.h>

// RelativeGridAttention: (B,H,Q,D)=(2,8,4096,32), grid 32x32 -> 1024 positions.
// v3: single pass (E cached packed-bf16), columns SPLIT across 4 waves per
// 16-row group -> only 32 VGPRs of E per lane. 16 waves/block, 64 rows/block.
// Keys bf16 in LDS with XOR chunk-swizzle (2-way conflicts, free) instead of
// the old 8-way row-stride conflict. Swapped-operand MFMA (refcheck'd in v2):
// lane owns 4 consecutive output cols of one query row -> float4 bias loads,
// float4 nontemporal stores, 2-shuffle quad reduction + 1KB LDS cross-wave sum.
namespace {
constexpr int B_ = 2, H_ = 8, Q_ = 4096, D_ = 32;
constexpr int NPOS = 1024;            // 32*32 key positions
constexpr int NB = 63;                // 2*32-1 rel_bias side
constexpr int NT = 1024;              // 16 waves = 4 row-groups x 4 col-waves
constexpr int QCHUNK = 64;            // 4 row-groups * 16 rows
constexpr float SCALE = 0.17677669529663687f;     // 1/sqrt(32)
constexpr float LOG2E = 1.4426950408889634f;
constexpr float C1 = SCALE * LOG2E;
}

typedef __attribute__((ext_vector_type(8))) short short8;   // 8 bf16, 4 VGPRs
typedef __attribute__((ext_vector_type(4))) float float4v;  // MFMA C/D

__device__ __forceinline__ unsigned short f2bf(float f) {   // fp32 -> bf16 RNE
  unsigned u = __float_as_uint(f);
  u += 0x7fffu + ((u >> 16) & 1u);
  return (unsigned short)(u >> 16);
}

__device__ __forceinline__ unsigned pack2bf(float a, float b) {
  return (unsigned)f2bf(a) | ((unsigned)f2bf(b) << 16);
}

__device__ __forceinline__ float fexp2(float x) {
#if defined(__has_builtin)
#if __has_builtin(__builtin_amdgcn_exp2f)
  return __builtin_amdgcn_exp2f(x);
#else
  return exp2f(x);
#endif
#else
  return exp2f(x);
#endif
}

__device__ __forceinline__ float frcp(float x) {
#if defined(__has_builtin)
#if __has_builtin(__builtin_amdgcn_rcpf)
  return __builtin_amdgcn_rcpf(x);
#else
  return 1.0f / x;
#endif
#else
  return 1.0f / x;
#endif
}

__device__ __forceinline__ unsigned pack_hi16(unsigned hi_from, unsigned lo_from) {
  // [15:0] = lo_from[31:16], [31:16] = hi_from[31:16]  (bf16 truncation pack)
#if defined(__has_builtin)
#if __has_builtin(__builtin_amdgcn_perm)
  return __builtin_amdgcn_perm(hi_from, lo_from, 0x07060302u);
#else
  return (lo_from >> 16) | (hi_from & 0xffff0000u);
#endif
#else
  return (lo_from >> 16) | (hi_from & 0xffff0000u);
#endif
}

__global__ __launch_bounds__(NT, 4)
void rga_kernel(const float* __restrict__ queries,
                const float* __restrict__ keys,
                const int*   __restrict__ pos,
                const float* __restrict__ rel_bias,
                float* __restrict__ out) {
  // keys tile, bf16, row p at byte p*64, 16B chunks XOR-swizzled by row.
  // After compute it is reused (first 1 KB) for the cross-wave sum exchange.
  __shared__ __align__(16) unsigned char klds[NPOS * 64];   // 64 KB

  const int t    = threadIdx.x;
  const int lane = t & 63;
  const int w    = t >> 6;          // wave id 0..15
  const int m    = lane & 15;       // query-row-within-group AND MFMA col
  const int quad = lane >> 4;       // 0..3
  const int rg   = w >> 2;          // row-group 0..3
  const int cw   = w & 3;           // col-wave 0..3 (owns tiles cw*16..cw*16+15)
  const int h  = blockIdx.y;
  const int b  = blockIdx.z;
  const int bh = b * H_ + h;
  const int q0 = blockIdx.x * QCHUNK;

  // ---- stage keys slice (b,h) as bf16 into LDS, chunk-swizzled ----
  {
    const float* src = keys + (size_t)bh * (NPOS * D_);
    #pragma unroll
    for (int i = 0; i < 4; ++i) {
      const int c = i * NT + t;          // 16B-chunk id 0..4095
      const int p = c >> 2;              // key row
      const int cq = c & 3;              // logical chunk within row
      float4 x = *(const float4*)(src + (size_t)c * 8);
      float4 y = *(const float4*)(src + (size_t)c * 8 + 4);
      uint4 v;
      v.x = pack2bf(x.x, x.y);
      v.y = pack2bf(x.z, x.w);
      v.z = pack2bf(y.x, y.y);
      v.w = pack2bf(y.z, y.w);
      const int pq = cq ^ (p & 3) ^ ((p >> 2) & 3);   // swizzled chunk
      *(uint4*)(klds + (size_t)p * 64 + pq * 16) = v;
    }
  }
  __syncthreads();

  const int qrow = q0 + rg * 16 + m;   // this lane's query row

  // A fragment (MFMA src1 / B-role): query row qrow, k = quad*8 + j
  short8 afrag;
  {
    const float* qp = queries + ((size_t)(bh * Q_) + qrow) * D_ + quad * 8;
    float4 x = *(const float4*)(qp);
    float4 y = *(const float4*)(qp + 4);
    afrag[0] = (short)f2bf(x.x); afrag[1] = (short)f2bf(x.y);
    afrag[2] = (short)f2bf(x.z); afrag[3] = (short)f2bf(x.w);
    afrag[4] = (short)f2bf(y.x); afrag[5] = (short)f2bf(y.y);
    afrag[6] = (short)f2bf(y.z); afrag[7] = (short)f2bf(y.w);
  }

  // per-lane bias base: output col p = n*16 + quad*4 + r
  // idx = [(31-py)*63 + (31-px) + quad*4] + (n>>1)*63 + ((n&1)<<4) + r
  const float* bbase;
  {
    int2 p = *(const int2*)(pos + ((size_t)b * Q_ + qrow) * 2);
    bbase = rel_bias + (size_t)h * (NB * NB)
          + (31 - p.x) * NB + (31 - p.y) + quad * 4;
  }

  // swizzled read base: row n*16+m, logical chunk = quad;
  // s(p) = (p&3)^((p>>2)&3); with p = n*16+m this is m-only (n*16 ≡ 0 mod 16).
  const unsigned char* kbase =
      klds + (size_t)m * 64 + ((quad ^ (m & 3) ^ ((m >> 2) & 3)) << 4);

  // ---- single pass over this wave's 16 column-tiles ----
  float sum = 0.f;
  unsigned Epk[32];                    // 64 exp values packed bf16
  #pragma unroll
  for (int k = 0; k < 16; ++k) {
    const int n = cw * 16 + k;
    const short8 kf = *(const short8*)(kbase + n * 1024);
    // swapped operands: acc[r] = S[qrow][n*16 + quad*4 + r]
    float4v acc = __builtin_amdgcn_mfma_f32_16x16x32_bf16(
        kf, afrag, (float4v){0.f, 0.f, 0.f, 0.f}, 0, 0, 0);
    float4v bv;
    __builtin_memcpy(&bv, bbase + (n >> 1) * NB + ((n & 1) << 4), 16);
    float e0 = fexp2(acc[0] * C1 + bv[0] * LOG2E);
    float e1 = fexp2(acc[1] * C1 + bv[1] * LOG2E);
    float e2 = fexp2(acc[2] * C1 + bv[2] * LOG2E);
    float e3 = fexp2(acc[3] * C1 + bv[3] * LOG2E);
    sum += (e0 + e1) + (e2 + e3);
    Epk[2 * k]     = pack_hi16(__float_as_uint(e1), __float_as_uint(e0));
    Epk[2 * k + 1] = pack_hi16(__float_as_uint(e3), __float_as_uint(e2));
  }

  // combine the 4 quads holding the same query row (wave's 256-col partial)
  sum += __shfl_xor(sum, 16, 64);
  sum += __shfl_xor(sum, 32, 64);

  // cross-wave (4 col-waves) row-sum via LDS; klds is dead now -> reuse it
  __syncthreads();                                 // all klds reads finished
  float* slds = (float*)klds;                      // [rg][cw][m] = 256 floats
  if (lane < 16) slds[w * 16 + m] = sum;           // lane<16 <=> quad==0, m=lane
  __syncthreads();
  const float full = (slds[rg * 64 + m]      + slds[rg * 64 + 16 + m]) +
                     (slds[rg * 64 + 32 + m] + slds[rg * 64 + 48 + m]);
  const float rinv = frcp(full);

  // ---- normalize from registers and store (float4, nontemporal) ----
  float* orow = out + ((size_t)(bh * Q_) + qrow) * NPOS + quad * 4;
  #pragma unroll
  for (int k = 0; k < 16; ++k) {
    const int n = cw * 16 + k;
    const unsigned ua = Epk[2 * k], ub = Epk[2 * k + 1];
    float4v ev;
    ev[0] = __uint_as_float(ua << 16)          * rinv;
    ev[1] = __uint_as_float(ua & 0xffff0000u)  * rinv;
    ev[2] = __uint_as_float(ub << 16)          * rinv;
    ev[3] = __uint_as_float(ub & 0xffff0000u)  * rinv;
    __builtin_nontemporal_store(ev, (float4v*)(orow + n * 16));
  }
}

extern "C" void kernel_launch(void* const* d_in, const int* in_sizes, int n_in,
                              void* d_out, int out_size, void* d_ws, size_t ws_size,
                              hipStream_t stream) {
  const float* queries  = (const float*)d_in[0];
  const float* keys     = (const float*)d_in[1];
  const int*   pos      = (const int*)d_in[2];
  const float* rel_bias = (const float*)d_in[3];
  float* out = (float*)d_out;

  dim3 grid(Q_ / QCHUNK, H_, B_);   // 64 x 8 x 2 = 1024 blocks
  dim3 block(NT);
  hipLaunchKernelGGL(rga_kernel, grid, block, 0, stream,
                     queries, keys, pos, rel_bias, out);
}

// Round 4
// 291.908 us; speedup vs baseline: 1.1630x; 1.1342x over previous
//
#include <hip/hip_runtime.h>

// RelativeGridAttention: (B,H,Q,D)=(2,8,4096,32), grid 32x32 -> 1024 positions.
// v4: two-phase per 16-row tile, transposing through LDS to decouple layouts.
//  Phase 1: MFMA (swapped operands, refcheck'd in v2/v3) using PRE-PACKED bf16
//           K fragments from workspace (prep kernel) -> coalesced 1KB L1-hot
//           loads; scores written fp32 to a 64KB LDS tile (XOR-swizzled b128).
//  Phase 2: ONE QUERY ROW PER WAVE -> bias reads are row-uniform+lane-contiguous
//           (8x128B segments/instr, the minimum -- kills the divergent gather
//           that was invariant across v1-v3), stores are 1KB-contiguous float4
//           nontemporal, row softmax = 6 shuffles.
// 512 thr/block, LDS 64KB -> 2 blocks/CU, 4 waves/SIMD.
namespace {
constexpr int B_ = 2, H_ = 8, Q_ = 4096, D_ = 32;
constexpr int NPOS = 1024;            // 32*32 key positions
constexpr int NB = 63;                // 2*32-1 rel_bias side
constexpr int NT = 512;               // 8 waves
constexpr int ROWTILE = 16;           // rows per LDS score tile
constexpr int TILES_PER_BLOCK = 8;    // 128 rows per block
constexpr int QCHUNK = ROWTILE * TILES_PER_BLOCK;
constexpr float SCALE = 0.17677669529663687f;     // 1/sqrt(32)
constexpr float LOG2E = 1.4426950408889634f;
constexpr float C1 = SCALE * LOG2E;
}

typedef __attribute__((ext_vector_type(8))) short short8;   // 8 bf16, 4 VGPRs
typedef __attribute__((ext_vector_type(4))) float float4v;  // MFMA C/D

__device__ __forceinline__ unsigned short f2bf(float f) {   // fp32 -> bf16 RNE
  unsigned u = __float_as_uint(f);
  u += 0x7fffu + ((u >> 16) & 1u);
  return (unsigned short)(u >> 16);
}

__device__ __forceinline__ unsigned pack2bf(float a, float b) {
  return (unsigned)f2bf(a) | ((unsigned)f2bf(b) << 16);
}

__device__ __forceinline__ float fexp2(float x) {
#if defined(__has_builtin)
#if __has_builtin(__builtin_amdgcn_exp2f)
  return __builtin_amdgcn_exp2f(x);
#else
  return exp2f(x);
#endif
#else
  return exp2f(x);
#endif
}

__device__ __forceinline__ float frcp(float x) {
#if defined(__has_builtin)
#if __has_builtin(__builtin_amdgcn_rcpf)
  return __builtin_amdgcn_rcpf(x);
#else
  return 1.0f / x;
#endif
#else
  return 1.0f / x;
#endif
}

// ---- prep: pack keys into ready-made bf16 MFMA fragments in workspace ----
// kws[bh][n][lane] (16 B) = K[bh][n*16 + (lane&15)][(lane>>4)*8 .. +7] as bf16.
__global__ __launch_bounds__(64)
void rga_prep(const float* __restrict__ keys, unsigned short* __restrict__ kws) {
  const int bid = blockIdx.x;          // bh*64 + n
  const int t   = threadIdx.x;         // lane 0..63
  const int m = t & 15, q = t >> 4;
  const int bh = bid >> 6, n = bid & 63;
  const float* src = keys + ((size_t)bh * NPOS + n * 16 + m) * D_ + q * 8;
  float4 x = *(const float4*)src;
  float4 y = *(const float4*)(src + 4);
  uint4 v;
  v.x = pack2bf(x.x, x.y);
  v.y = pack2bf(x.z, x.w);
  v.z = pack2bf(y.x, y.y);
  v.w = pack2bf(y.z, y.w);
  *(uint4*)(kws + ((size_t)bid * 64 + t) * 8) = v;   // coalesced 16 B/lane
}

__global__ __launch_bounds__(NT, 4)
void rga_main(const float* __restrict__ queries,
              const unsigned short* __restrict__ kws,
              const int*   __restrict__ pos,
              const float* __restrict__ rel_bias,
              float* __restrict__ out) {
  __shared__ __align__(16) float slds[ROWTILE * NPOS];   // 64 KB fp32 scores

  const int t    = threadIdx.x;
  const int lane = t & 63;
  const int w    = t >> 6;          // wave 0..7
  const int m    = lane & 15;       // row within tile (phase 1)
  const int quad = lane >> 4;       // 0..3
  const int h  = blockIdx.y;
  const int b  = blockIdx.z;
  const int bh = b * H_ + h;
  const int q0 = blockIdx.x * QCHUNK;

  const unsigned short* kbh = kws + (size_t)bh * (64 * 64 * 8);
  const float* bias_h = rel_bias + (size_t)h * (NB * NB);

  for (int tile = 0; tile < TILES_PER_BLOCK; ++tile) {
    const int qt0 = q0 + tile * ROWTILE;

    // ---- phase 1: MFMA scores for 16 rows; wave w owns col-tiles w*8..w*8+7 ----
    short8 afrag;   // Q row qt0+m, k = quad*8 + j (same fragment as v2/v3)
    {
      const float* qp = queries + ((size_t)(bh * Q_) + qt0 + m) * D_ + quad * 8;
      float4 x = *(const float4*)(qp);
      float4 y = *(const float4*)(qp + 4);
      afrag[0] = (short)f2bf(x.x); afrag[1] = (short)f2bf(x.y);
      afrag[2] = (short)f2bf(x.z); afrag[3] = (short)f2bf(x.w);
      afrag[4] = (short)f2bf(y.x); afrag[5] = (short)f2bf(y.y);
      afrag[6] = (short)f2bf(y.z); afrag[7] = (short)f2bf(y.w);
    }
    #pragma unroll
    for (int k = 0; k < 8; ++k) {
      const int n = w * 8 + k;
      const short8 kf = *(const short8*)(kbh + ((size_t)n * 64 + lane) * 8);
      // swapped operands (refcheck'd): acc[r] = S[qt0+m][n*16 + quad*4 + r]
      float4v acc = __builtin_amdgcn_mfma_f32_16x16x32_bf16(
          kf, afrag, (float4v){0.f, 0.f, 0.f, 0.f}, 0, 0, 0);
      // scores[m][cols n*16+quad*4 ..+3], byte off XOR-swizzled by row
      const int off = (n * 64 + quad * 16) ^ (m << 4);
      *(float4v*)((char*)slds + m * 4096 + off) = acc;
    }
    __syncthreads();

    // ---- phase 2: one row per wave iteration; rows lr = 2w, 2w+1 ----
    #pragma unroll
    for (int rr = 0; rr < 2; ++rr) {
      const int lr   = w * 2 + rr;
      const int qrow = qt0 + lr;
      int2 p = *(const int2*)(pos + ((size_t)b * Q_ + qrow) * 2);
      const float* brow = bias_h + (31 - p.x) * NB + (31 - p.y);
      // lane covers cols c = n2*256 + lane*4 ..+3 -> i = n2*8+(lane>>3),
      // j = (lane&7)*4 ..+3 (always within one 32-col bias row)
      const int ioff = (lane >> 3) * NB + (lane & 7) * 4;

      float e[16];
      float sum = 0.f;
      #pragma unroll
      for (int n2 = 0; n2 < 4; ++n2) {
        const int off = (n2 * 1024 + lane * 16) ^ (lr << 4);
        float4v s4 = *(const float4v*)((char*)slds + lr * 4096 + off);
        float4v bv;
        __builtin_memcpy(&bv, brow + n2 * 8 * NB + ioff, 16);
        float e0 = fexp2(s4[0] * C1 + bv[0] * LOG2E);
        float e1 = fexp2(s4[1] * C1 + bv[1] * LOG2E);
        float e2 = fexp2(s4[2] * C1 + bv[2] * LOG2E);
        float e3 = fexp2(s4[3] * C1 + bv[3] * LOG2E);
        e[n2 * 4 + 0] = e0; e[n2 * 4 + 1] = e1;
        e[n2 * 4 + 2] = e2; e[n2 * 4 + 3] = e3;
        sum += (e0 + e1) + (e2 + e3);
      }
      #pragma unroll
      for (int mask = 1; mask <= 32; mask <<= 1)
        sum += __shfl_xor(sum, mask, 64);
      const float rinv = frcp(sum);

      float* orow = out + ((size_t)(bh * Q_) + qrow) * NPOS;
      #pragma unroll
      for (int n2 = 0; n2 < 4; ++n2) {
        float4v ev;
        ev[0] = e[n2 * 4 + 0] * rinv;
        ev[1] = e[n2 * 4 + 1] * rinv;
        ev[2] = e[n2 * 4 + 2] * rinv;
        ev[3] = e[n2 * 4 + 3] * rinv;
        __builtin_nontemporal_store(ev, (float4v*)(orow + n2 * 256 + lane * 4));
      }
    }
    __syncthreads();   // protect slds before next tile's phase 1
  }
}

extern "C" void kernel_launch(void* const* d_in, const int* in_sizes, int n_in,
                              void* d_out, int out_size, void* d_ws, size_t ws_size,
                              hipStream_t stream) {
  const float* queries  = (const float*)d_in[0];
  const float* keys     = (const float*)d_in[1];
  const int*   pos      = (const int*)d_in[2];
  const float* rel_bias = (const float*)d_in[3];
  float* out = (float*)d_out;
  unsigned short* kws = (unsigned short*)d_ws;   // needs 1 MiB of workspace

  // prep: 16 bh * 64 col-tiles = 1024 blocks of 64 threads
  hipLaunchKernelGGL(rga_prep, dim3(B_ * H_ * 64), dim3(64), 0, stream,
                     keys, kws);
  // main: 32 x 8 x 2 = 512 blocks = 2/CU
  dim3 grid(Q_ / QCHUNK, H_, B_);
  dim3 block(NT);
  hipLaunchKernelGGL(rga_main, grid, block, 0, stream,
                     queries, kws, pos, rel_bias, out);
}